// Round 1
// baseline (893.580 us; speedup 1.0000x reference)
//
#include <hip/hip_runtime.h>

#define NN 8192      // nodes
#define NG 128       // graphs
#define NF 128       // input feats
#define CL 512       // hidden dim
#define ZD 1536      // concat dim (3*512)
#define NE 262144    // edges per edge set

// ---------------- degree / dense adjacency ----------------
__global__ void deg_kernel(const int* __restrict__ dst, float* __restrict__ deg) {
    int e = blockIdx.x * 256 + threadIdx.x;
    atomicAdd(&deg[dst[e]], 1.0f);
}

__global__ void deg_finish(float* __restrict__ deg, float* __restrict__ dinv) {
    int n = blockIdx.x * 256 + threadIdx.x;
    float d = deg[n] + 1.0f;
    deg[n] = d;
    dinv[n] = rsqrtf(d);
}

__global__ void build_adj(const int* __restrict__ src, const int* __restrict__ dst,
                          const float* __restrict__ dinv, float* __restrict__ A) {
    int e = blockIdx.x * 256 + threadIdx.x;
    int s = src[e], d = dst[e];
    int g = d >> 6;
    atomicAdd(&A[(size_t)((g << 6) + (d & 63)) * 64 + (s & 63)], dinv[s] * dinv[d]);
}

__global__ void adj_diag(const float* __restrict__ deg, float* __restrict__ A) {
    int n = blockIdx.x * 256 + threadIdx.x;
    int g = n >> 6, i = n & 63;
    A[(size_t)(g * 64 + i) * 64 + i] += 1.0f / deg[n];
}

// ---------------- generic tiled f32 GEMM: C = A(MxK)@B(KxN) (+bias)(+act) ----------------
// 64x64 tile, BK=32, 256 threads, 4x4 per thread. Grid: (N/64, M/64).
// ACT: 0 none, 1 relu, 2 leaky(0.01)
template<int ACT, bool HASB>
__global__ __launch_bounds__(256)
void gemm_f32(const float* __restrict__ A, int lda,
              const float* __restrict__ B, int ldb,
              float* __restrict__ C, int ldc,
              const float* __restrict__ bias, int K)
{
    __shared__ float As[32][68];   // [k][m]
    __shared__ float Bs[32][68];   // [k][n]
    const int tid = threadIdx.x;
    const int bm = blockIdx.y * 64, bn = blockIdx.x * 64;
    const int tx = tid & 15, ty = tid >> 4;
    float acc[4][4] = {};
    for (int k0 = 0; k0 < K; k0 += 32) {
        #pragma unroll
        for (int idx = tid; idx < 2048; idx += 256) {
            int m = idx >> 5, kk = idx & 31;
            As[kk][m] = A[(size_t)(bm + m) * lda + k0 + kk];
        }
        #pragma unroll
        for (int idx = tid; idx < 2048; idx += 256) {
            int kk = idx >> 6, n = idx & 63;
            Bs[kk][n] = B[(size_t)(k0 + kk) * ldb + bn + n];
        }
        __syncthreads();
        #pragma unroll
        for (int kk = 0; kk < 32; ++kk) {
            float4 a = *(const float4*)&As[kk][ty * 4];
            float4 b = *(const float4*)&Bs[kk][tx * 4];
            float av[4] = {a.x, a.y, a.z, a.w};
            float bv[4] = {b.x, b.y, b.z, b.w};
            #pragma unroll
            for (int i = 0; i < 4; ++i)
                #pragma unroll
                for (int j = 0; j < 4; ++j)
                    acc[i][j] = fmaf(av[i], bv[j], acc[i][j]);
        }
        __syncthreads();
    }
    #pragma unroll
    for (int i = 0; i < 4; ++i) {
        int r = bm + ty * 4 + i;
        #pragma unroll
        for (int j = 0; j < 4; ++j) {
            int c = bn + tx * 4 + j;
            float v = acc[i][j];
            if (HASB) v += bias[c];
            if (ACT == 1) v = v > 0.f ? v : 0.f;
            if (ACT == 2) v = v > 0.f ? v : 0.01f * v;
            C[(size_t)r * ldc + c] = v;
        }
    }
}

// ---------------- batch norm ----------------
__global__ void bn_stats(const float* __restrict__ h, int ldh,
                         float* __restrict__ sums, float* __restrict__ sqs)
{
    int c = blockIdx.x * 256 + threadIdx.x;     // 0..511
    int r0 = blockIdx.y * 256;
    float s = 0.f, q = 0.f;
    for (int r = r0; r < r0 + 256; ++r) {
        float v = h[(size_t)r * ldh + c];
        s += v;
        q = fmaf(v, v, q);
    }
    atomicAdd(&sums[c], s);
    atomicAdd(&sqs[c], q);
}

__global__ void bn_apply(const float* __restrict__ h, int ldh, float* __restrict__ o,
                         const float* __restrict__ sums, const float* __restrict__ sqs,
                         const float* __restrict__ g, const float* __restrict__ b)
{
    int idx = blockIdx.x * 256 + threadIdx.x;   // over NN*CL
    int c = idx & (CL - 1);
    int r = idx >> 9;
    float m = sums[c] * (1.0f / NN);
    float var = sqs[c] * (1.0f / NN) - m * m;
    float inv = rsqrtf(var + 1e-5f);
    o[(size_t)r * CL + c] = (h[(size_t)r * ldh + c] - m) * inv * g[c] + b[c];
}

// ---------------- GCN combine: out = relu(A_g @ H2_g + b), batched ----------------
// grid (NG, CL/64), 256 threads
__global__ __launch_bounds__(256)
void gcn_combine(const float* __restrict__ A, const float* __restrict__ H2,
                 const float* __restrict__ bias, float* __restrict__ out)
{
    int g = blockIdx.x, ct = blockIdx.y;
    __shared__ float At[64][68];   // At[k][i] = A[i][k]
    __shared__ float Hs[64][68];   // [k][c]
    int tid = threadIdx.x;
    const float* Ag = A + (size_t)g * 4096;
    for (int idx = tid; idx < 4096; idx += 256) {
        int i = idx >> 6, k = idx & 63;
        At[k][i] = Ag[idx];        // Ag[i*64+k]
    }
    for (int idx = tid; idx < 4096; idx += 256) {
        int k = idx >> 6, c = idx & 63;
        Hs[k][c] = H2[(size_t)(g * 64 + k) * CL + ct * 64 + c];
    }
    __syncthreads();
    int tx = tid & 15, ty = tid >> 4;
    float acc[4][4] = {};
    #pragma unroll
    for (int k = 0; k < 64; ++k) {
        float4 a = *(const float4*)&At[k][ty * 4];
        float4 b = *(const float4*)&Hs[k][tx * 4];
        float av[4] = {a.x, a.y, a.z, a.w};
        float bv[4] = {b.x, b.y, b.z, b.w};
        #pragma unroll
        for (int i = 0; i < 4; ++i)
            #pragma unroll
            for (int j = 0; j < 4; ++j)
                acc[i][j] = fmaf(av[i], bv[j], acc[i][j]);
    }
    #pragma unroll
    for (int i = 0; i < 4; ++i) {
        int node = g * 64 + ty * 4 + i;
        #pragma unroll
        for (int j = 0; j < 4; ++j) {
            int c = ct * 64 + tx * 4 + j;
            float v = acc[i][j] + bias[c];
            v = v > 0.f ? v : 0.f;
            out[(size_t)node * ZD + c] = v;   // out pre-offset by layer*CL
        }
    }
}

// ---------------- per-graph Gram matrix G = Z_g Z_g^T ----------------
__global__ __launch_bounds__(256)
void gram_kernel(const float* __restrict__ Z, float* __restrict__ G)
{
    int g = blockIdx.x;
    __shared__ float Zs[32][68];   // [k][node]
    int tid = threadIdx.x, tx = tid & 15, ty = tid >> 4;
    float acc[4][4] = {};
    for (int k0 = 0; k0 < ZD; k0 += 32) {
        for (int idx = tid; idx < 2048; idx += 256) {
            int i = idx >> 5, kk = idx & 31;
            Zs[kk][i] = Z[(size_t)(g * 64 + i) * ZD + k0 + kk];
        }
        __syncthreads();
        #pragma unroll
        for (int kk = 0; kk < 32; ++kk) {
            float4 a = *(const float4*)&Zs[kk][ty * 4];
            float4 b = *(const float4*)&Zs[kk][tx * 4];
            float av[4] = {a.x, a.y, a.z, a.w};
            float bv[4] = {b.x, b.y, b.z, b.w};
            #pragma unroll
            for (int i = 0; i < 4; ++i)
                #pragma unroll
                for (int j = 0; j < 4; ++j)
                    acc[i][j] = fmaf(av[i], bv[j], acc[i][j]);
        }
        __syncthreads();
    }
    #pragma unroll
    for (int i = 0; i < 4; ++i)
        #pragma unroll
        for (int j = 0; j < 4; ++j)
            G[(size_t)(g * 64 + ty * 4 + i) * 64 + tx * 4 + j] = acc[i][j];
}

// ---------------- edge loss ----------------
__global__ void edge_loss(const int* __restrict__ e0, const int* __restrict__ e1,
                          const float* __restrict__ G, float* __restrict__ tot,
                          float* __restrict__ cnt, int negmode)
{
    __shared__ float lt[128];
    __shared__ float lc[128];
    int tid = threadIdx.x;
    if (tid < 128) { lt[tid] = 0.f; lc[tid] = 0.f; }
    __syncthreads();
    for (int e = blockIdx.x * blockDim.x + tid; e < NE; e += gridDim.x * blockDim.x) {
        int a = e0[e], b = e1[e];
        int g = a >> 6;
        float v = G[(size_t)((g << 6) + (a & 63)) * 64 + (b & 63)];
        float s = 1.f / (1.f + expf(-v));
        float p = negmode ? (1.f - s) : s;
        float l = -logf(1e-4f + p);
        atomicAdd(&lt[g], l);
        atomicAdd(&lc[g], 1.f);
    }
    __syncthreads();
    if (tid < 128) {
        atomicAdd(&tot[tid], lt[tid]);
        atomicAdd(&cnt[tid], lc[tid]);
    }
}

__global__ void lrc_final(const float* __restrict__ loss, float* __restrict__ out)
{
    int t = threadIdx.x;   // 128
    float v = loss[t] / fmaxf(loss[128 + t], 1.f) + loss[256 + t] / fmaxf(loss[384 + t], 1.f);
    __shared__ float red[128];
    red[t] = v;
    __syncthreads();
    for (int s = 64; s; s >>= 1) {
        if (t < s) red[t] += red[t + s];
        __syncthreads();
    }
    if (t == 0) out[0] = red[0] * (1.0f / 128.0f);
}

// ---------------- attention scores s1,s2 ----------------
__global__ void s12_kernel(const float* __restrict__ xh, const float* __restrict__ phi,
                           float* __restrict__ s1, float* __restrict__ s2)
{
    int idx = blockIdx.x * 256 + threadIdx.x;   // n*8+h
    int n = idx >> 3, h = idx & 7;
    const float* xr = xh + (size_t)n * 512 + h * 64;
    const float* pa = phi + h * 128;
    const float* pb = pa + 64;
    float a = 0.f, b = 0.f;
    #pragma unroll
    for (int d = 0; d < 64; ++d) {
        float v = xr[d];
        a = fmaf(v, pa[d], a);
        b = fmaf(v, pb[d], b);
    }
    s1[idx] = a;
    s2[idx] = b;
}

// ---------------- attention aggregation: per (graph, head) 64x64 @ 64x64 ----------------
__global__ __launch_bounds__(256)
void attn_agg(const float* __restrict__ xh, const float* __restrict__ s1,
              const float* __restrict__ s2, float* __restrict__ agg)
{
    int g = blockIdx.x, h = blockIdx.y;
    __shared__ float Wt[64][68];   // Wt[b][i] = w(i,b)
    __shared__ float Xs[64][68];   // [b][d]
    __shared__ float s1s[64], s2s[64];
    int tid = threadIdx.x;
    if (tid < 64) {
        s1s[tid] = s1[(size_t)(g * 64 + tid) * 8 + h];
        s2s[tid] = s2[(size_t)(g * 64 + tid) * 8 + h];
    }
    __syncthreads();
    for (int idx = tid; idx < 4096; idx += 256) {
        int b = idx >> 6, i = idx & 63;
        float t = s1s[i] + s2s[b];
        t = t > 0.f ? t : 0.01f * t;
        Wt[b][i] = 1.f / (1.f + expf(-t));
    }
    for (int idx = tid; idx < 4096; idx += 256) {
        int b = idx >> 6, d = idx & 63;
        Xs[b][d] = xh[(size_t)(g * 64 + b) * 512 + h * 64 + d];
    }
    __syncthreads();
    int tx = tid & 15, ty = tid >> 4;
    float acc[4][4] = {};
    #pragma unroll
    for (int b = 0; b < 64; ++b) {
        float4 a = *(const float4*)&Wt[b][ty * 4];
        float4 x = *(const float4*)&Xs[b][tx * 4];
        float av[4] = {a.x, a.y, a.z, a.w};
        float xv[4] = {x.x, x.y, x.z, x.w};
        #pragma unroll
        for (int i = 0; i < 4; ++i)
            #pragma unroll
            for (int j = 0; j < 4; ++j)
                acc[i][j] = fmaf(av[i], xv[j], acc[i][j]);
    }
    #pragma unroll
    for (int i = 0; i < 4; ++i) {
        int node = g * 64 + ty * 4 + i;
        #pragma unroll
        for (int j = 0; j < 4; ++j)
            agg[(size_t)node * 512 + h * 64 + tx * 4 + j] = acc[i][j];
    }
}

// ---------------- classifier head: logits -> softmax-ish preds ----------------
__global__ void head_kernel(const float* __restrict__ hid, const float* __restrict__ fc2W,
                            const float* __restrict__ fc2b, float* __restrict__ preds)
{
    int n = blockIdx.x * 256 + threadIdx.x;
    const float* hr = hid + (size_t)n * 64;
    float x[64];
    #pragma unroll
    for (int k = 0; k < 64; ++k) x[k] = hr[k];
    float lg[10];
    float mx = -1e30f;
    #pragma unroll
    for (int c = 0; c < 10; ++c) {
        float s = fc2b[c];
        #pragma unroll
        for (int k = 0; k < 64; ++k) s = fmaf(x[k], fc2W[k * 10 + c], s);
        lg[c] = s;
        mx = fmaxf(mx, s);
    }
    float sum = 0.f;
    #pragma unroll
    for (int c = 0; c < 10; ++c) {
        float t = expf(lg[c] - mx) + 1e-4f;
        lg[c] = t;
        sum += t;
    }
    float inv = 1.f / sum;
    #pragma unroll
    for (int c = 0; c < 10; ++c) preds[(size_t)n * 10 + c] = lg[c] * inv;
}

// ---------------- per-graph mean of preds -> log ----------------
__global__ void yp_kernel(const float* __restrict__ preds, float* __restrict__ out)
{
    int g = blockIdx.x;
    int lane = threadIdx.x;   // 64
    float p[10];
    const float* pr = preds + (size_t)(g * 64 + lane) * 10;
    #pragma unroll
    for (int c = 0; c < 10; ++c) p[c] = pr[c];
    #pragma unroll
    for (int off = 32; off; off >>= 1)
        #pragma unroll
        for (int c = 0; c < 10; ++c) p[c] += __shfl_down(p[c], off);
    if (lane == 0)
        #pragma unroll
        for (int c = 0; c < 10; ++c) out[g * 10 + c] = logf(p[c] * (1.0f / 64.0f));
}

extern "C" void kernel_launch(void* const* d_in, const int* in_sizes, int n_in,
                              void* d_out, int out_size, void* d_ws, size_t ws_size,
                              hipStream_t stream)
{
    (void)in_sizes; (void)n_in; (void)out_size; (void)ws_size;
    const float* x     = (const float*)d_in[0];
    const int*   ei    = (const int*)d_in[1];
    const int*   nei   = (const int*)d_in[2];
    const float* fcW   = (const float*)d_in[5];
    const float* fcb   = (const float*)d_in[6];
    const float* bng   = (const float*)d_in[7];
    const float* bnb   = (const float*)d_in[8];
    const float* convW = (const float*)d_in[9];
    const float* convb = (const float*)d_in[10];
    const float* featW = (const float*)d_in[11];
    const float* phi   = (const float*)d_in[12];
    const float* fc1W  = (const float*)d_in[13];
    const float* fc1b  = (const float*)d_in[14];
    const float* fc2W  = (const float*)d_in[15];
    const float* fc2b  = (const float*)d_in[16];
    float* out = (float*)d_out;

    char* ws = (char*)d_ws;
    float* Z    = (float*)(ws);               // 8192*1536 = 48 MB
    float* HPRE = (float*)(ws + 50331648);    // 8192*512  (also HID later)
    float* HBN  = (float*)(ws + 67108864);    // 8192*512  (also XH later)
    float* H2   = (float*)(ws + 83886080);    // 8192*512  (also AGG later)
    float* DEG  = (float*)(ws + 100663296);   // 8192
    float* DINV = (float*)(ws + 100696064);   // 8192
    float* Amat = (float*)(ws + 100728832);   // 128*64*64
    float* Gram = (float*)(ws + 102825984);   // 128*64*64
    float* BNS  = (float*)(ws + 104923136);   // 1024
    float* LOSS = (float*)(ws + 104927232);   // 512
    float* S12  = (float*)(ws + 104929280);   // 8192*16
    float* HID  = HPRE;

    const int* src = ei;
    const int* dst = ei + NE;

    hipMemsetAsync(DEG, 0, NN * 4, stream);
    hipMemsetAsync(Amat, 0, (size_t)NG * 64 * 64 * 4, stream);
    hipMemsetAsync(LOSS, 0, 512 * 4, stream);

    deg_kernel<<<NE / 256, 256, 0, stream>>>(dst, DEG);
    deg_finish<<<NN / 256, 256, 0, stream>>>(DEG, DINV);
    build_adj<<<NE / 256, 256, 0, stream>>>(src, dst, DINV, Amat);
    adj_diag<<<NN / 256, 256, 0, stream>>>(DEG, Amat);

    // h0 = x @ fc_W + fc_b
    gemm_f32<0, true><<<dim3(CL / 64, NN / 64), 256, 0, stream>>>(
        x, NF, fcW, CL, HPRE, CL, fcb, NF);

    for (int i = 0; i < 3; ++i) {
        const float* hin = (i == 0) ? HPRE : (Z + (size_t)(i - 1) * CL);
        int ldin = (i == 0) ? CL : ZD;
        hipMemsetAsync(BNS, 0, 1024 * 4, stream);
        bn_stats<<<dim3(2, 32), 256, 0, stream>>>(hin, ldin, BNS, BNS + 512);
        bn_apply<<<(NN * CL) / 256, 256, 0, stream>>>(hin, ldin, HBN, BNS, BNS + 512,
                                                      bng + i * CL, bnb + i * CL);
        gemm_f32<0, false><<<dim3(CL / 64, NN / 64), 256, 0, stream>>>(
            HBN, CL, convW + (size_t)i * CL * CL, CL, H2, CL, nullptr, CL);
        gcn_combine<<<dim3(NG, CL / 64), 256, 0, stream>>>(Amat, H2, convb + i * CL,
                                                           Z + (size_t)i * CL);
    }

    // edge reconstruction loss via per-graph Gram matrices
    gram_kernel<<<NG, 256, 0, stream>>>(Z, Gram);
    edge_loss<<<128, 256, 0, stream>>>(ei, ei + NE, Gram, LOSS, LOSS + 128, 0);
    edge_loss<<<128, 256, 0, stream>>>(nei, nei + NE, Gram, LOSS + 256, LOSS + 384, 1);
    lrc_final<<<1, 128, 0, stream>>>(LOSS, out + 1280);

    // xh = z @ feat_W
    gemm_f32<0, false><<<dim3(CL / 64, NN / 64), 256, 0, stream>>>(
        Z, ZD, featW, CL, HBN, CL, nullptr, ZD);
    s12_kernel<<<(NN * 8) / 256, 256, 0, stream>>>(HBN, phi, S12, S12 + NN * 8);
    attn_agg<<<dim3(NG, 8), 256, 0, stream>>>(HBN, S12, S12 + NN * 8, H2);

    // hid = leaky_relu(agg @ fc1 + b)
    gemm_f32<2, true><<<dim3(1, NN / 64), 256, 0, stream>>>(
        H2, CL, fc1W, 64, HID, 64, fc1b, CL);
    head_kernel<<<NN / 256, 256, 0, stream>>>(HID, fc2W, fc2b, out + 1281);
    yp_kernel<<<NG, 64, 0, stream>>>(out + 1281, out);
}